// Round 7
// baseline (149.746 us; speedup 1.0000x reference)
//
#include <hip/hip_runtime.h>

// DepthwiseTemporalConv: I[n,c,t] = x_flat[n*16384 + c*64 + t]
// Y[n,c,t] = sum_{k=0}^{63-t} I[n,c,t+k] * W[c,k]
// out_flat[(n>>10)*16777216 + c*65536 + t*1024 + (n&1023)] = Y[n,c,t]
//
// R6 (resubmit — infra failure last round): half-row pipelined staging.
// Per wave: ONE 8.3KB LDS buffer, reused for both 32-float halves of each
// lane's row. stage H1 -> drain -> read+PIN H1 -> issue H2 (same buffer) ->
// T1 compute under H2 latency -> vmcnt(0) -> read H2 -> cross -> store t<32
// -> T2 -> store t>=32. No __syncthreads (waves fully independent, wave-local
// vmcnt only). LDS 33.3KB/block -> 4 blocks/CU = 16 waves/CU (R5 was ~7).
// xh pins are mandatory for correctness: hipcc re-reads LDS lazily (R5
// VGPR=68 with a "64-float" array) and H2 overwrites the buffer.

constexpr int Cc = 256;
constexpr int Tt = 64;
constexpr int Kk = 64;
constexpr int CT = Cc * Tt;              // 16384
constexpr int CS = 1024 + 16;            // 1KB chunk + pad (R1's 0-conflict stride)
constexpr int WAVE_LDS = 8 * CS;         // 8320 B: one half-tile per wave
constexpr int LDS_BYTES = 4 * WAVE_LDS;  // 33280 B/block -> 4 blocks/CU

__global__ __launch_bounds__(256, 4)
void DepthwiseTemporalConv_24962349924982_kernel(const float* __restrict__ x,
                                                 const float* __restrict__ w,
                                                 float* __restrict__ out) {
    __shared__ __align__(16) char lds[LDS_BYTES];
    const int tid  = threadIdx.x;
    const int lane = tid & 63;
    const int wv   = tid >> 6;

    const int n_tile = blockIdx.x & 63;   // 64 n-tiles
    const int c_tile = blockIdx.x >> 6;   // 64 c-tiles
    const int n0 = n_tile * 64;
    const int n  = n0 + lane;
    const int cu = __builtin_amdgcn_readfirstlane(c_tile * 4 + wv);

    char* wbase = lds + wv * WAVE_LDS;
    const int srow = lane >> 3;           // row-within-8 this lane sources
    const int scol = (lane & 7) * 4;      // float offset within the 32-float half

    // ---- stage H1: instr i gathers rows n0+8i..+7, first 128B of each row's
    // c-slice, into a linear 1KB LDS chunk (per-lane global src, uniform dest).
    #pragma unroll
    for (int i = 0; i < 8; ++i) {
        const float* gsrc = x + (size_t)(n0 + 8 * i + srow) * CT
                              + (size_t)cu * Tt + scol;
        __builtin_amdgcn_global_load_lds(
            (const __attribute__((address_space(1))) void*)gsrc,
            (__attribute__((address_space(3))) void*)(wbase + i * CS),
            16, 0, 0);
    }

    // ---- weights: wave-uniform -> scalar loads into SGPRs
    float wr[Kk];
    {
        const float4* wp = (const float4*)(w + (size_t)cu * Kk);
        #pragma unroll
        for (int m = 0; m < 16; ++m) {
            const float4 v = wp[m];
            wr[4*m+0] = v.x; wr[4*m+1] = v.y; wr[4*m+2] = v.z; wr[4*m+3] = v.w;
        }
    }

    asm volatile("s_waitcnt vmcnt(0)" ::: "memory");   // H1 landed (wave-local)
    __builtin_amdgcn_sched_barrier(0);

    // ---- read H1 half-row into regs and PIN (buffer about to be reused)
    const char* rbase = wbase + (lane >> 3) * CS + (lane & 7) * 128;
    float xh[32];
    #pragma unroll
    for (int m = 0; m < 8; ++m) {
        const float4 v = *(const float4*)(rbase + m * 16);
        xh[4*m+0] = v.x; xh[4*m+1] = v.y; xh[4*m+2] = v.z; xh[4*m+3] = v.w;
    }
    asm volatile("s_waitcnt lgkmcnt(0)" ::: "memory"); // reads done before overwrite
    __builtin_amdgcn_sched_barrier(0);
    #pragma unroll
    for (int m = 0; m < 8; ++m)
        asm volatile("" : "+v"(xh[4*m+0]), "+v"(xh[4*m+1]),
                          "+v"(xh[4*m+2]), "+v"(xh[4*m+3]));

    // ---- issue H2 into the SAME buffer (latency hidden under T1)
    #pragma unroll
    for (int i = 0; i < 8; ++i) {
        const float* gsrc = x + (size_t)(n0 + 8 * i + srow) * CT
                              + (size_t)cu * Tt + 32 + scol;
        __builtin_amdgcn_global_load_lds(
            (const __attribute__((address_space(1))) void*)gsrc,
            (__attribute__((address_space(3))) void*)(wbase + i * CS),
            16, 0, 0);
    }
    __builtin_amdgcn_sched_barrier(0);

    // ---- T1: acc[t] (t<32) over H1, j-outer streaming (independent t-chains)
    float acc[32];
    #pragma unroll
    for (int t = 0; t < 32; ++t) acc[t] = 0.f;
    #pragma unroll
    for (int j = 0; j < 32; ++j) {
        const float xv = xh[j];
        #pragma unroll
        for (int t = 0; t <= j; ++t)
            acc[t] = fmaf(xv, wr[j - t], acc[t]);
    }

    asm volatile("s_waitcnt vmcnt(0)" ::: "memory");   // H2 landed
    __builtin_amdgcn_sched_barrier(0);

    // ---- read H2 (buffer stable from here on: remat/re-read harmless)
    float xh2[32];
    #pragma unroll
    for (int m = 0; m < 8; ++m) {
        const float4 v = *(const float4*)(rbase + m * 16);
        xh2[4*m+0] = v.x; xh2[4*m+1] = v.y; xh2[4*m+2] = v.z; xh2[4*m+3] = v.w;
    }

    // ---- cross: acc[t] += x[32+j] * w[32+j-t], full 32x32
    #pragma unroll
    for (int j = 0; j < 32; ++j) {
        const float xv = xh2[j];
        #pragma unroll
        for (int t = 0; t < 32; ++t)
            acc[t] = fmaf(xv, wr[32 + j - t], acc[t]);
    }

    // ---- store t = 0..31 (256B contiguous per instr per wave)
    float* __restrict__ obase = out + (size_t)(n >> 10) * (Cc * Tt * 1024)
                                    + (size_t)cu * (Tt * 1024) + (n & 1023);
    #pragma unroll
    for (int t = 0; t < 32; ++t)
        obase[(size_t)t * 1024] = acc[t];

    // ---- T2: t = 32..63, triangular over H2 only
    float acc2[32];
    #pragma unroll
    for (int t = 0; t < 32; ++t) acc2[t] = 0.f;
    #pragma unroll
    for (int j = 0; j < 32; ++j) {
        const float xv = xh2[j];
        #pragma unroll
        for (int t = 0; t <= j; ++t)
            acc2[t] = fmaf(xv, wr[j - t], acc2[t]);
    }
    #pragma unroll
    for (int t = 0; t < 32; ++t)
        obase[(size_t)(32 + t) * 1024] = acc2[t];
}

extern "C" void kernel_launch(void* const* d_in, const int* in_sizes, int n_in,
                              void* d_out, int out_size, void* d_ws, size_t ws_size,
                              hipStream_t stream) {
    const float* x = (const float*)d_in[0];
    const float* w = (const float*)d_in[1];
    float* out = (float*)d_out;
    DepthwiseTemporalConv_24962349924982_kernel<<<dim3(4096), dim3(256), 0, stream>>>(x, w, out);
}

// Round 9
// 144.836 us; speedup vs baseline: 1.0339x; 1.0339x over previous
//
#include <hip/hip_runtime.h>

// DepthwiseTemporalConv: I[n,c,t] = x_flat[n*16384 + c*64 + t]
// Y[n,c,t] = sum_{k=0}^{63-t} I[n,c,t+k] * W[c,k]
// out_flat[(n>>10)*16777216 + c*65536 + t*1024 + (n&1023)] = Y[n,c,t]
//
// R7 (resubmit — infra failure): no LDS, no barriers. Each thread loads its
// contiguous 256B row with 16 inline-asm global_load_dwordx4 — an asm def is
// opaque, so hipcc CANNOT rematerialize it (R2/R3 failure) and holds xr[64]
// in VGPRs (R1 proved the t-outer structure compiles faithfully at VGPR=88).
// One vmcnt(0) + sched_barrier(0) (rule #18), then triangular compute +
// coalesced stores. Residency: ~96 VGPR -> 5 waves/SIMD = 20 waves/CU, each
// with 16KB of loads in flight ~35% of its life -> ~100KB/CU outstanding,
// removing the MLP wall that capped R1-R6 at ~2.5 TB/s / ~150us.

constexpr int Cc = 256;
constexpr int Tt = 64;
constexpr int Kk = 64;
constexpr int CT = Cc * Tt;   // 16384

typedef float f32x4 __attribute__((ext_vector_type(4)));

__global__ __launch_bounds__(128, 5)
void DepthwiseTemporalConv_24962349924982_kernel(const float* __restrict__ x,
                                                 const float* __restrict__ w,
                                                 float* __restrict__ out) {
    const int tid = threadIdx.x;
    const int bid = blockIdx.x;
    const int c      = bid & 255;         // block-uniform channel
    const int n_tile = bid >> 8;          // 32 n-tiles of 128 rows
    const int n  = n_tile * 128 + tid;
    const int cu = __builtin_amdgcn_readfirstlane(c);

    // ---- issue 16 opaque loads for this thread's contiguous 256B row.
    // Per wave-instr: 64 lanes x 16B = 1KB; 16 in flight = 16KB/wave.
    const float* rowp = x + (size_t)n * CT + (size_t)cu * Tt;
    f32x4 q[16];
    #pragma unroll
    for (int m = 0; m < 16; ++m) {
        asm volatile("global_load_dwordx4 %0, %1, off offset:%2"
                     : "=v"(q[m])
                     : "v"(rowp), "i"(16 * m));
    }

    // ---- weights: block-uniform -> scalar s_loads into SGPRs
    float wr[Kk];
    {
        const float4* wp = (const float4*)(w + (size_t)cu * Kk);
        #pragma unroll
        for (int m = 0; m < 16; ++m) {
            const float4 v = wp[m];
            wr[4*m+0] = v.x; wr[4*m+1] = v.y; wr[4*m+2] = v.z; wr[4*m+3] = v.w;
        }
    }

    // ---- drain the 16 loads; fence scheduler so no consumer hoists above
    asm volatile("s_waitcnt vmcnt(0)" ::: "memory");
    __builtin_amdgcn_sched_barrier(0);

    // register-rename q -> xr (no LDS, no copies after regalloc)
    float xr[Tt];
    #pragma unroll
    for (int m = 0; m < 16; ++m) {
        xr[4*m+0] = q[m][0]; xr[4*m+1] = q[m][1];
        xr[4*m+2] = q[m][2]; xr[4*m+3] = q[m][3];
    }

    // ---- triangular suffix correlation (R1's faithful structure),
    // 2 accumulator chains; stores 256B-contiguous per wave per t.
    float* __restrict__ obase = out + (size_t)(n >> 10) * (Cc * Tt * 1024)
                                    + (size_t)cu * (Tt * 1024) + (n & 1023);
    #pragma unroll
    for (int t = 0; t < Tt; ++t) {
        const int len = Tt - t;
        float a0 = 0.f, a1 = 0.f;
        #pragma unroll
        for (int k = 0; k + 1 < len; k += 2) {
            a0 = fmaf(xr[t + k],     wr[k],     a0);
            a1 = fmaf(xr[t + k + 1], wr[k + 1], a1);
        }
        if (len & 1) a0 = fmaf(xr[Tt - 1], wr[len - 1], a0);
        obase[(size_t)t * 1024] = a0 + a1;
    }
}

extern "C" void kernel_launch(void* const* d_in, const int* in_sizes, int n_in,
                              void* d_out, int out_size, void* d_ws, size_t ws_size,
                              hipStream_t stream) {
    const float* x = (const float*)d_in[0];
    const float* w = (const float*)d_in[1];
    float* out = (float*)d_out;
    // 32 n-tiles x 256 c = 8192 two-wave blocks
    DepthwiseTemporalConv_24962349924982_kernel<<<dim3(8192), dim3(128), 0, stream>>>(x, w, out);
}